// Round 7
// baseline (234.960 us; speedup 1.0000x reference)
//
#include <hip/hip_runtime.h>

// SpriteAssembler via MFMA, operand-swapped, identity-folded:
//   ACC[64i][16px] = W'[64i][64k] x B[64k][16px]   (f16 in, f32 acc)
// W part:   W[i][j] = tanh(relu(d_j - d_i)),  B[j][px] = log2(1 - s[px][j])
// id part:  acc[it] += Id x log2(s)  -- one extra MFMA per 16-row i-tile.
// masks = exp2(ACC) row-normalized (+eps).
// R7: R6 + FORCED 2-deep load pipeline: inline-asm global_load_dwordx4
//     (compiler can't track -> can't collapse), manual counted s_waitcnt
//     vmcnt(N) per tile (never 0 in loop), sched_barrier after each wait.
//     Store path unchanged: LDS-transposed, 4 x 1KB lane-contiguous stores.

typedef __attribute__((ext_vector_type(8))) _Float16 half8;
typedef __attribute__((ext_vector_type(4))) float floatx4;

#define EPSF 1e-6f

__device__ inline float fast_exp2(float x){ return __builtin_amdgcn_exp2f(x); }
__device__ inline float fast_log2(float x){ return __builtin_amdgcn_logf(x); }  // log2
__device__ inline float fast_rcp (float x){ return __builtin_amdgcn_rcpf(x); }

// 4 x 16B loads from one base address (+0,+16,+128,+144 bytes).
// Results are NOT valid until the matching WAITVM.
#define ALOAD(d0, d1, d2, d3, addr)                                           \
    asm volatile("global_load_dwordx4 %0, %4, off\n\t"                        \
                 "global_load_dwordx4 %1, %4, off offset:16\n\t"              \
                 "global_load_dwordx4 %2, %4, off offset:128\n\t"             \
                 "global_load_dwordx4 %3, %4, off offset:144"                 \
                 : "=v"(d0), "=v"(d1), "=v"(d2), "=v"(d3)                     \
                 : "v"(addr) : "memory")

#define WAITVM(N)                                                             \
    do {                                                                      \
        asm volatile("s_waitcnt vmcnt(" #N ")" ::: "memory");                 \
        __builtin_amdgcn_sched_barrier(0);                                    \
    } while (0)

__global__ __launch_bounds__(256, 2) void sprite_mfma_kernel(
    const float* __restrict__ shapes,   // [8, 65536, 64]
    const float* __restrict__ depths,   // [8, 64]
    float* __restrict__ out)            // [8, 65536, 64]
{
    const int wave  = threadIdx.x >> 6;
    const int lane  = threadIdx.x & 63;
    const int batch = blockIdx.x >> 7;   // 128 blocks per batch
    const int rblk  = blockIdx.x & 127;
    const int wid   = rblk * 4 + wave;   // wave id within batch [0,512), 128 px each

    __shared__ float dsh[64];
    __shared__ __align__(16) float ustage[4][16][68];  // per-wave u-tile, +4 pad

    if (threadIdx.x < 64) dsh[threadIdx.x] = depths[batch * 64 + threadIdx.x];
    __syncthreads();

    const int c = lane & 15;   // A: m(i-local). B: n(px). D: col(px)
    const int q = lane >> 4;   // k-quad / D row group

    const long pxbase = (long)batch * 65536 + (long)wid * 128;
    const float* sp = shapes + (pxbase + c) * 64 + q * 8;  // lane's chunk, tile 0
    float* const obase0 = out + pxbase * 64;               // wave's contiguous 32KB

    // ---- forced 2-deep prefetch: issue tiles 0 and 1 now ----
    floatx4 LA0, LA1, LA2, LA3, LB0, LB1, LB2, LB3;
    ALOAD(LA0, LA1, LA2, LA3, sp);
    ALOAD(LB0, LB1, LB2, LB3, sp + 1024);

    // ---- W fragments (A-operand), built under the prefetches' flight ----
    half8 Aw[4][2];
    #pragma unroll
    for (int it = 0; it < 4; ++it) {
        float di = dsh[it * 16 + c];
        #pragma unroll
        for (int kt = 0; kt < 2; ++kt) {
            half8 h;
            #pragma unroll
            for (int jj = 0; jj < 8; ++jj) {
                int j = kt * 32 + q * 8 + jj;
                float x = fmaxf(dsh[j] - di, 0.0f);            // relu(d_j - d_i)
                float e = fast_exp2(x * 2.885390082f);         // e^{2x}
                h[jj] = (_Float16)((e - 1.0f) * fast_rcp(e + 1.0f));  // tanh
            }
            Aw[it][kt] = h;
        }
    }
    // identity A-fragments: nonzero only where k_local == (it&1)*16 + m
    half8 idlo, idhi;
    #pragma unroll
    for (int jj = 0; jj < 8; ++jj) {
        idlo[jj] = (q * 8 + jj == c)      ? (_Float16)1.0f : (_Float16)0.0f;
        idhi[jj] = (q * 8 + jj == 16 + c) ? (_Float16)1.0f : (_Float16)0.0f;
    }

    auto process = [&](floatx4 s0, floatx4 s1, floatx4 s2, floatx4 s3, int tile) {
        float sv[16] = {s0[0], s0[1], s0[2], s0[3], s1[0], s1[1], s1[2], s1[3],
                        s2[0], s2[1], s2[2], s2[3], s3[0], s3[1], s3[2], s3[3]};
        half8 B_lo, B_hi;                        // B[j][px=c]  = log2(1 - s)
        half8 C_lo, C_hi;                        // B2[j][px=c] = log2(s)
        #pragma unroll
        for (int e = 0; e < 8; ++e) {
            float slo = fminf(fmaxf(sv[e],     EPSF), 1.0f - EPSF);
            float shi = fminf(fmaxf(sv[8 + e], EPSF), 1.0f - EPSF);
            B_lo[e] = (_Float16)fast_log2(1.0f - slo);
            B_hi[e] = (_Float16)fast_log2(1.0f - shi);
            C_lo[e] = (_Float16)fast_log2(slo);
            C_hi[e] = (_Float16)fast_log2(shi);
        }

        floatx4 acc[4];
        #pragma unroll
        for (int it = 0; it < 4; ++it) {
            floatx4 a = {0.f, 0.f, 0.f, 0.f};
            a = __builtin_amdgcn_mfma_f32_16x16x32_f16(Aw[it][0], B_lo, a, 0, 0, 0);
            a = __builtin_amdgcn_mfma_f32_16x16x32_f16(Aw[it][1], B_hi, a, 0, 0, 0);
            a = __builtin_amdgcn_mfma_f32_16x16x32_f16(
                    (it & 1) ? idhi : idlo, (it < 2) ? C_lo : C_hi, a, 0, 0, 0);
            acc[it] = a;
        }

        // D layout: value (it, r) is ACC[i = it*16 + q*4 + r][px = tile*16 + c]
        float u[4][4];
        float tot = 0.f;
        #pragma unroll
        for (int it = 0; it < 4; ++it) {
            #pragma unroll
            for (int r = 0; r < 4; ++r) {
                float v = fast_exp2(acc[it][r]);
                u[it][r] = v;
                tot += v;
            }
        }
        tot += __shfl_xor(tot, 16, 64);          // reduce over q-groups (all 64 i)
        tot += __shfl_xor(tot, 32, 64);
        float inv = fast_rcp(tot + EPSF);

        // ---- LDS transpose epilogue (per-wave private; no barriers) ----
        #pragma unroll
        for (int it = 0; it < 4; ++it) {
            floatx4 o = {u[it][0] * inv, u[it][1] * inv,
                         u[it][2] * inv, u[it][3] * inv};
            *(floatx4*)&ustage[wave][c][it * 16 + q * 4] = o;
        }
        // store-linear: instr k covers global bytes [k*1024 + lane*16)
        float* ob = obase0 + (long)tile * 16 * 64;
        #pragma unroll
        for (int k = 0; k < 4; ++k) {
            floatx4 o = *(const floatx4*)&ustage[wave][k * 4 + q][c * 4];
            *(floatx4*)(ob + k * 256 + lane * 4) = o;
        }
    };

    // Per tile i: wait for L(i) (counted; younger ops stay in flight),
    // grab the set, refill it with L(i+2), compute+store.
    // Queue at top of tile i (oldest->newest): L(i),S(i-2),L(i+1),S(i-1) -> 12.
#define TILE_A(T, NW, DOLOAD)                                                 \
    do {                                                                      \
        WAITVM(NW);                                                           \
        floatx4 s0 = LA0, s1 = LA1, s2 = LA2, s3 = LA3;                       \
        if (DOLOAD) ALOAD(LA0, LA1, LA2, LA3, sp + ((T) + 2) * 1024);         \
        process(s0, s1, s2, s3, (T));                                         \
    } while (0)
#define TILE_B(T, NW, DOLOAD)                                                 \
    do {                                                                      \
        WAITVM(NW);                                                           \
        floatx4 s0 = LB0, s1 = LB1, s2 = LB2, s3 = LB3;                       \
        if (DOLOAD) ALOAD(LB0, LB1, LB2, LB3, sp + ((T) + 2) * 1024);         \
        process(s0, s1, s2, s3, (T));                                         \
    } while (0)

    TILE_A(0,  4, 1);
    TILE_B(1,  8, 1);
    TILE_A(2, 12, 1);
    TILE_B(3, 12, 1);
    TILE_A(4, 12, 1);
    TILE_B(5, 12, 1);
    TILE_A(6, 12, 0);
    TILE_B(7,  8, 0);

#undef TILE_A
#undef TILE_B
}

extern "C" void kernel_launch(void* const* d_in, const int* in_sizes, int n_in,
                              void* d_out, int out_size, void* d_ws, size_t ws_size,
                              hipStream_t stream) {
    const float* shapes = (const float*)d_in[0];
    const float* depths = (const float*)d_in[1];
    float* out = (float*)d_out;
    // 8 batches * 128 blocks, 256 threads (4 waves), 128 px per wave
    sprite_mfma_kernel<<<1024, 256, 0, stream>>>(shapes, depths, out);
}

// Round 8
// 232.582 us; speedup vs baseline: 1.0102x; 1.0102x over previous
//
#include <hip/hip_runtime.h>

// SpriteAssembler via MFMA, operand-swapped, identity-folded:
//   ACC[64i][16px] = W'[64i][64k] x B[64k][16px]   (f16 in, f32 acc)
// W part:   W[i][j] = tanh(relu(d_j - d_i)),  B[j][px] = log2(1 - s[px][j])
// id part:  acc[it] += Id x log2(s)  -- one extra MFMA per 16-row i-tile.
// masks = exp2(ACC) row-normalized (+eps).
// R8: R6 store path (LDS-transposed, 4 x 1KB lane-contiguous stores) with
//     CLEAN occupancy doubling: 2048 blocks x 256 thr, 64 px/wave, 4 tiles.
//     17.9KB LDS/block -> exactly 8 blocks/CU = 32 waves/CU nominal (2x R6).
//     No other changes (no NT stores, no gather stream -- the R1/R3 confounds).

typedef __attribute__((ext_vector_type(8))) _Float16 half8;
typedef __attribute__((ext_vector_type(4))) float floatx4;

#define EPSF 1e-6f

__device__ inline float fast_exp2(float x){ return __builtin_amdgcn_exp2f(x); }
__device__ inline float fast_log2(float x){ return __builtin_amdgcn_logf(x); }  // log2
__device__ inline float fast_rcp (float x){ return __builtin_amdgcn_rcpf(x); }

__global__ __launch_bounds__(256, 2) void sprite_mfma_kernel(
    const float* __restrict__ shapes,   // [8, 65536, 64]
    const float* __restrict__ depths,   // [8, 64]
    float* __restrict__ out)            // [8, 65536, 64]
{
    const int wave  = threadIdx.x >> 6;
    const int lane  = threadIdx.x & 63;
    const int batch = blockIdx.x >> 8;   // 256 blocks per batch
    const int rblk  = blockIdx.x & 255;
    const int wid   = rblk * 4 + wave;   // wave id within batch [0,1024), 64 px each

    __shared__ float dsh[64];
    __shared__ __align__(16) float ustage[4][16][68];  // per-wave u-tile, +4 pad

    if (threadIdx.x < 64) dsh[threadIdx.x] = depths[batch * 64 + threadIdx.x];
    __syncthreads();

    const int c = lane & 15;   // A: m(i-local). B: n(px). D: col(px)
    const int q = lane >> 4;   // k-quad / D row group

    // ---- W fragments (A-operand), built once per wave ----
    half8 Aw[4][2];
    #pragma unroll
    for (int it = 0; it < 4; ++it) {
        float di = dsh[it * 16 + c];
        #pragma unroll
        for (int kt = 0; kt < 2; ++kt) {
            half8 h;
            #pragma unroll
            for (int jj = 0; jj < 8; ++jj) {
                int j = kt * 32 + q * 8 + jj;
                float x = fmaxf(dsh[j] - di, 0.0f);            // relu(d_j - d_i)
                float e = fast_exp2(x * 2.885390082f);         // e^{2x}
                h[jj] = (_Float16)((e - 1.0f) * fast_rcp(e + 1.0f));  // tanh
            }
            Aw[it][kt] = h;
        }
    }

    // identity A-fragments: nonzero only where k_local == (it&1)*16 + m
    half8 idlo, idhi;
    #pragma unroll
    for (int jj = 0; jj < 8; ++jj) {
        idlo[jj] = (q * 8 + jj == c)      ? (_Float16)1.0f : (_Float16)0.0f;
        idhi[jj] = (q * 8 + jj == 16 + c) ? (_Float16)1.0f : (_Float16)0.0f;
    }

    const long pxbase = (long)batch * 65536 + (long)wid * 64;
    const float* sp = shapes + (pxbase + c) * 64 + q * 8;  // lane's row chunk, tile 0
    float* const obase0 = out + pxbase * 64;               // wave's contiguous 16KB

    // B-layout loads: lane reads s[px=c][q*8 .. q*8+7] and the +32 block.
    float4 pf0 = *(const float4*)(sp);
    float4 pf1 = *(const float4*)(sp + 4);
    float4 pf2 = *(const float4*)(sp + 32);
    float4 pf3 = *(const float4*)(sp + 36);

    for (int tile = 0; tile < 4; ++tile) {
        float4 s0 = pf0, s1 = pf1, s2 = pf2, s3 = pf3;
        if (tile < 3) {                          // software prefetch next tile
            const float* sn = sp + (tile + 1) * 16 * 64;
            pf0 = *(const float4*)(sn);
            pf1 = *(const float4*)(sn + 4);
            pf2 = *(const float4*)(sn + 32);
            pf3 = *(const float4*)(sn + 36);
        }

        float sv[16] = {s0.x, s0.y, s0.z, s0.w, s1.x, s1.y, s1.z, s1.w,
                        s2.x, s2.y, s2.z, s2.w, s3.x, s3.y, s3.z, s3.w};
        half8 B_lo, B_hi;                        // B[j][px=c]  = log2(1 - s)
        half8 C_lo, C_hi;                        // B2[j][px=c] = log2(s)
        #pragma unroll
        for (int e = 0; e < 8; ++e) {
            float slo = fminf(fmaxf(sv[e],     EPSF), 1.0f - EPSF);
            float shi = fminf(fmaxf(sv[8 + e], EPSF), 1.0f - EPSF);
            B_lo[e] = (_Float16)fast_log2(1.0f - slo);
            B_hi[e] = (_Float16)fast_log2(1.0f - shi);
            C_lo[e] = (_Float16)fast_log2(slo);
            C_hi[e] = (_Float16)fast_log2(shi);
        }

        floatx4 acc[4];
        #pragma unroll
        for (int it = 0; it < 4; ++it) {
            floatx4 a = {0.f, 0.f, 0.f, 0.f};
            a = __builtin_amdgcn_mfma_f32_16x16x32_f16(Aw[it][0], B_lo, a, 0, 0, 0);
            a = __builtin_amdgcn_mfma_f32_16x16x32_f16(Aw[it][1], B_hi, a, 0, 0, 0);
            a = __builtin_amdgcn_mfma_f32_16x16x32_f16(
                    (it & 1) ? idhi : idlo, (it < 2) ? C_lo : C_hi, a, 0, 0, 0);
            acc[it] = a;
        }

        // D layout: value (it, r) is ACC[i = it*16 + q*4 + r][px = tile*16 + c]
        float u[4][4];
        float tot = 0.f;
        #pragma unroll
        for (int it = 0; it < 4; ++it) {
            #pragma unroll
            for (int r = 0; r < 4; ++r) {
                float v = fast_exp2(acc[it][r]);
                u[it][r] = v;
                tot += v;
            }
        }
        tot += __shfl_xor(tot, 16, 64);          // reduce over q-groups (all 64 i)
        tot += __shfl_xor(tot, 32, 64);
        float inv = fast_rcp(tot + EPSF);

        // ---- LDS transpose epilogue (per-wave private; no barriers) ----
        // write D-layout: row px=c, i-cols it*16+q*4 .. +4
        #pragma unroll
        for (int it = 0; it < 4; ++it) {
            floatx4 o = {u[it][0] * inv, u[it][1] * inv,
                         u[it][2] * inv, u[it][3] * inv};
            *(floatx4*)&ustage[wave][c][it * 16 + q * 4] = o;
        }
        // read store-linear: instr k covers global bytes [k*1024 + lane*16)
        // px = k*4 + q, i-cols c*4 .. +4. Tile output is contiguous 4KB.
        float* ob = obase0 + (long)tile * 16 * 64;
        #pragma unroll
        for (int k = 0; k < 4; ++k) {
            floatx4 o = *(const floatx4*)&ustage[wave][k * 4 + q][c * 4];
            *(floatx4*)(ob + k * 256 + lane * 4) = o;
        }
    }
}

extern "C" void kernel_launch(void* const* d_in, const int* in_sizes, int n_in,
                              void* d_out, int out_size, void* d_ws, size_t ws_size,
                              hipStream_t stream) {
    const float* shapes = (const float*)d_in[0];
    const float* depths = (const float*)d_in[1];
    float* out = (float*)d_out;
    // 8 batches * 256 blocks, 256 threads (4 waves), 64 px per wave
    sprite_mfma_kernel<<<2048, 256, 0, stream>>>(shapes, depths, out);
}